// Round 1
// baseline (100.231 us; speedup 1.0000x reference)
//
#include <hip/hip_runtime.h>
#include <limits.h>
#include <math.h>

// Problem constants (match reference setup_inputs)
#define BB 4
#define NN 6300
#define NCLS 80
#define PSTRIDE 85
#define CONF_TH 0.5f
#define NMS_TH 0.4f
#define CAP 2048   // per-(image,class) bucket capacity; expected ~40, ultra-safe

// ---------------------------------------------------------------------------
// Kernel 1: per-box decode + det output (with bbox_fit) + record staging
// ---------------------------------------------------------------------------
__global__ void __launch_bounds__(256) prep_kernel(
    const float* __restrict__ pred,
    const int* __restrict__ fhp, const int* __restrict__ fwp,
    float* __restrict__ det_out,     // [BB*NN*7]
    float* __restrict__ keep_out,    // [BB*NN]
    int*   __restrict__ cls_ws,      // [BB*NN]  (-1 if below conf thresh)
    float* __restrict__ score_ws,    // [BB*NN]
    float* __restrict__ ox1_ws, float* __restrict__ oy1_ws,
    float* __restrict__ ox2_ws, float* __restrict__ oy2_ws)
{
  int gid = blockIdx.x * blockDim.x + threadIdx.x;
  if (gid >= BB * NN) return;
  const float* p = pred + (long)gid * PSTRIDE;

  float cx = p[0], cy = p[1], w = p[2], h = p[3], obj = p[4];
  // products by 0.5f are exact -> FMA contraction harmless here
  float x1 = cx - 0.5f * w;
  float y1 = cy - 0.5f * h;
  float x2 = cx + 0.5f * w;
  float y2 = cy + 0.5f * h;

  // argmax over 80 classes (first max, like jnp.argmax)
  float cmax = p[5];
  int cidx = 0;
  for (int j = 1; j < NCLS; ++j) {
    float v = p[5 + j];
    if (v > cmax) { cmax = v; cidx = j; }
  }

  // bbox_fit constants (computed in double; exact for 720/1280: pad=(0,70), s=(4,4))
  double fh = (double)fhp[0], fw = (double)fwp[0];
  const double ihd = 320.0, iwd = 320.0;
  double fdim = fmax(fh, fw);
  double pad_x_d = fmax((fh * iwd / ihd - fw) / 2.0, 0.0) * iwd / fdim;
  double pad_y_d = fmax((fw * ihd / iwd - fh) / 2.0, 0.0) * ihd / fdim;
  float sx = (float)(fw / (iwd - 2.0 * pad_x_d));
  float sy = (float)(fh / (ihd - 2.0 * pad_y_d));
  float px = (float)pad_x_d, py = (float)pad_y_d;
  float fwf = (float)fw, fhf = (float)fh;

  float* d = det_out + (long)gid * 7;
  // (x - pad) * s : sub feeds mul, no contraction possible; clip = min(max(v,0),lim)
  d[0] = fminf(fmaxf((x1 - px) * sx, 0.0f), fwf);
  d[1] = fminf(fmaxf((y1 - py) * sy, 0.0f), fhf);
  d[2] = fminf(fmaxf((x2 - px) * sx, 0.0f), fwf);
  d[3] = fminf(fmaxf((y2 - py) * sy, 0.0f), fhf);
  d[4] = obj;
  d[5] = cmax;
  d[6] = (float)cidx;

  keep_out[gid] = 0.0f;

  bool valid = obj >= CONF_TH;
  cls_ws[gid] = valid ? cidx : -1;
  score_ws[gid] = obj;
  // offset coords, f32-rounded exactly like reference's oboxes = boxes + cls*10000
  float off = (float)cidx * 10000.0f;   // exact product (<2^24, integer)
  ox1_ws[gid] = x1 + off;
  oy1_ws[gid] = y1 + off;
  ox2_ws[gid] = x2 + off;
  oy2_ws[gid] = y2 + off;
}

// ---------------------------------------------------------------------------
// Kernel 2: per-(image,class) gather -> bitonic sort -> greedy NMS
// ---------------------------------------------------------------------------
__global__ void __launch_bounds__(256) nms_kernel(
    const int*   __restrict__ cls_ws,
    const float* __restrict__ score_ws,
    const float* __restrict__ ox1_ws, const float* __restrict__ oy1_ws,
    const float* __restrict__ ox2_ws, const float* __restrict__ oy2_ws,
    float* __restrict__ keep_out)
{
  __shared__ float s_sc[CAP];
  __shared__ float s_x1[CAP], s_y1[CAP], s_x2[CAP], s_y2[CAP];
  __shared__ int   s_idx[CAP];
  __shared__ unsigned char s_sup[CAP];
  __shared__ int s_cnt;

  const int b = blockIdx.x / NCLS;
  const int c = blockIdx.x % NCLS;
  const int tid = threadIdx.x;
  const int base = b * NN;

  if (tid == 0) s_cnt = 0;
  __syncthreads();

  // gather this bucket's valid boxes
  for (int n = tid; n < NN; n += 256) {
    if (cls_ws[base + n] == c) {
      int pos = atomicAdd(&s_cnt, 1);
      if (pos < CAP) {
        s_sc[pos]  = score_ws[base + n];
        s_idx[pos] = n;
        s_x1[pos]  = ox1_ws[base + n];
        s_y1[pos]  = oy1_ws[base + n];
        s_x2[pos]  = ox2_ws[base + n];
        s_y2[pos]  = oy2_ws[base + n];
      }
    }
  }
  __syncthreads();
  int cnt = min(s_cnt, CAP);
  if (cnt == 0) return;

  // pad to power of two
  int M = 1;
  while (M < cnt) M <<= 1;
  for (int i = cnt + tid; i < M; i += 256) {
    s_sc[i] = -INFINITY;
    s_idx[i] = INT_MAX;
    s_x1[i] = 0.0f; s_y1[i] = 0.0f; s_x2[i] = 0.0f; s_y2[i] = 0.0f;
  }
  __syncthreads();

  // bitonic sort: (score desc, idx asc) — matches stable argsort(-score)
  for (int k = 2; k <= M; k <<= 1) {
    for (int j = k >> 1; j > 0; j >>= 1) {
      for (int i = tid; i < M; i += 256) {
        int ixj = i ^ j;
        if (ixj > i) {
          float si = s_sc[i], sj = s_sc[ixj];
          int ii = s_idx[i], ij = s_idx[ixj];
          bool before_ij = (si > sj) || (si == sj && ii < ij); // e[i] precedes e[ixj]
          bool before_ji = (sj > si) || (sj == si && ij < ii);
          bool up = ((i & k) == 0);
          bool dosw = up ? before_ji : before_ij;
          if (dosw) {
            s_sc[i] = sj;  s_sc[ixj] = si;
            s_idx[i] = ij; s_idx[ixj] = ii;
            float t;
            t = s_x1[i]; s_x1[i] = s_x1[ixj]; s_x1[ixj] = t;
            t = s_y1[i]; s_y1[i] = s_y1[ixj]; s_y1[ixj] = t;
            t = s_x2[i]; s_x2[i] = s_x2[ixj]; s_x2[ixj] = t;
            t = s_y2[i]; s_y2[i] = s_y2[ixj]; s_y2[ixj] = t;
          }
        }
      }
      __syncthreads();
    }
  }

  for (int i = tid; i < cnt; i += 256) s_sup[i] = 0;
  __syncthreads();

  // greedy NMS — bit-exact f32 replication of reference IoU (no FMA contraction)
  for (int i = 0; i < cnt; ++i) {
    if (!s_sup[i]) {
      float x1i = s_x1[i], y1i = s_y1[i], x2i = s_x2[i], y2i = s_y2[i];
      float ai = __fmul_rn(__fadd_rn(__fsub_rn(x2i, x1i), 1.0f),
                           __fadd_rn(__fsub_rn(y2i, y1i), 1.0f));
      if (tid == 0) keep_out[base + s_idx[i]] = 1.0f;
      for (int j = i + 1 + tid; j < cnt; j += 256) {
        float iw_ = __fadd_rn(__fsub_rn(fminf(x2i, s_x2[j]), fmaxf(x1i, s_x1[j])), 1.0f);
        iw_ = fmaxf(iw_, 0.0f);
        float ih_ = __fadd_rn(__fsub_rn(fminf(y2i, s_y2[j]), fmaxf(y1i, s_y1[j])), 1.0f);
        ih_ = fmaxf(ih_, 0.0f);
        float inter = __fmul_rn(iw_, ih_);
        float aj = __fmul_rn(__fadd_rn(__fsub_rn(s_x2[j], s_x1[j]), 1.0f),
                             __fadd_rn(__fsub_rn(s_y2[j], s_y1[j]), 1.0f));
        float denom = __fadd_rn(__fsub_rn(__fadd_rn(ai, aj), inter), 1e-16f);
        float iou = __fdiv_rn(inter, denom);
        if (iou >= NMS_TH) s_sup[j] = 1;
      }
    }
    __syncthreads();
  }
}

// ---------------------------------------------------------------------------
extern "C" void kernel_launch(void* const* d_in, const int* in_sizes, int n_in,
                              void* d_out, int out_size, void* d_ws, size_t ws_size,
                              hipStream_t stream) {
  const float* pred = (const float*)d_in[0];
  const int* fhp = (const int*)d_in[1];
  const int* fwp = (const int*)d_in[2];

  float* det_out  = (float*)d_out;                       // BB*NN*7
  float* keep_out = det_out + (size_t)BB * NN * 7;       // BB*NN

  // workspace layout (6 arrays of BB*NN 4-byte elems = 604,800 B)
  const size_t stride = (size_t)BB * NN;
  int*   cls_ws   = (int*)d_ws;
  float* f_ws     = (float*)d_ws;
  float* score_ws = f_ws + stride;
  float* ox1_ws   = f_ws + 2 * stride;
  float* oy1_ws   = f_ws + 3 * stride;
  float* ox2_ws   = f_ws + 4 * stride;
  float* oy2_ws   = f_ws + 5 * stride;

  int nThreads = BB * NN;
  prep_kernel<<<(nThreads + 255) / 256, 256, 0, stream>>>(
      pred, fhp, fwp, det_out, keep_out,
      cls_ws, score_ws, ox1_ws, oy1_ws, ox2_ws, oy2_ws);

  nms_kernel<<<BB * NCLS, 256, 0, stream>>>(
      cls_ws, score_ws, ox1_ws, oy1_ws, ox2_ws, oy2_ws, keep_out);
}

// Round 4
// 84.502 us; speedup vs baseline: 1.1861x; 1.1861x over previous
//
#include <hip/hip_runtime.h>
#include <limits.h>
#include <math.h>

// Problem constants (match reference setup_inputs)
#define BB 4
#define NN 6300
#define NCLS 80
#define NB (BB * NCLS)          // 320 (image,class) buckets
#define PSTRIDE 85
#define CONF_TH 0.5f
#define NMS_TH 0.4f
#define CAP2 512                // bucket capacity; expected ~39/bucket

// Workspace layout (ws is ~268 MB):
//   [0, 1280)       cnt_ws : NB ints
//   [4096, ~3.9MB)  rec_ws : NB * CAP2 * 6 floats {x1o,y1o,x2o,y2o,score,n_bits}
// (R3 crash root-cause: rec_ws previously started at byte 1024, aliasing
//  cnt_ws[256..319] -> poisoned s_idx -> wild keep_out writes -> GPU fault.)

// ---------------------------------------------------------------------------
// Kernel 0: zero the bucket counters (graph-capture-safe, no memset API)
// ---------------------------------------------------------------------------
__global__ void __launch_bounds__(320) zero_kernel(int* __restrict__ cnt_ws) {
  cnt_ws[threadIdx.x] = 0;
}

// ---------------------------------------------------------------------------
// Kernel 1: decode + det output (bbox_fit) + direct bucket scatter
// ---------------------------------------------------------------------------
__global__ void __launch_bounds__(256) prep_kernel(
    const float* __restrict__ pred,
    const int* __restrict__ fhp, const int* __restrict__ fwp,
    float* __restrict__ det_out,     // [BB*NN*7]
    float* __restrict__ keep_out,    // [BB*NN]
    int*   __restrict__ cnt_ws,
    float* __restrict__ rec_ws)
{
  int gid = blockIdx.x * blockDim.x + threadIdx.x;
  if (gid >= BB * NN) return;
  const float* p = pred + (long)gid * PSTRIDE;

  float cx = p[0], cy = p[1], w = p[2], h = p[3], obj = p[4];
  // 0.5f products exact -> FMA contraction harmless
  float x1 = cx - 0.5f * w;
  float y1 = cy - 0.5f * h;
  float x2 = cx + 0.5f * w;
  float y2 = cy + 0.5f * h;

  // first-max argmax over 80 classes (matches jnp.argmax)
  float cmax = p[5];
  int cidx = 0;
  for (int j = 1; j < NCLS; ++j) {
    float v = p[5 + j];
    if (v > cmax) { cmax = v; cidx = j; }
  }

  // bbox_fit constants in double (exact for 720/1280: pad=(0,70), s=(4,4))
  double fh = (double)fhp[0], fw = (double)fwp[0];
  const double ihd = 320.0, iwd = 320.0;
  double fdim = fmax(fh, fw);
  double pad_x_d = fmax((fh * iwd / ihd - fw) / 2.0, 0.0) * iwd / fdim;
  double pad_y_d = fmax((fw * ihd / iwd - fh) / 2.0, 0.0) * ihd / fdim;
  float sx = (float)(fw / (iwd - 2.0 * pad_x_d));
  float sy = (float)(fh / (ihd - 2.0 * pad_y_d));
  float px = (float)pad_x_d, py = (float)pad_y_d;
  float fwf = (float)fw, fhf = (float)fh;

  float* d = det_out + (long)gid * 7;
  d[0] = fminf(fmaxf((x1 - px) * sx, 0.0f), fwf);
  d[1] = fminf(fmaxf((y1 - py) * sy, 0.0f), fhf);
  d[2] = fminf(fmaxf((x2 - px) * sx, 0.0f), fwf);
  d[3] = fminf(fmaxf((y2 - py) * sy, 0.0f), fhf);
  d[4] = obj;
  d[5] = cmax;
  d[6] = (float)cidx;

  keep_out[gid] = 0.0f;

  if (obj >= CONF_TH) {
    int b = gid / NN;
    int n = gid - b * NN;
    int bucket = b * NCLS + cidx;
    int pos = atomicAdd(&cnt_ws[bucket], 1);
    if (pos < CAP2) {
      float off = (float)cidx * 10000.0f;   // exact product
      float* r = rec_ws + ((size_t)bucket * CAP2 + pos) * 6;
      r[0] = x1 + off;   // f32-rounded exactly like reference oboxes
      r[1] = y1 + off;
      r[2] = x2 + off;
      r[3] = y2 + off;
      r[4] = obj;
      r[5] = __int_as_float(n);
    }
  }
}

// ---------------------------------------------------------------------------
// Kernel 2: 1 wave per bucket — register bitonic sort + ballot greedy NMS.
// Block = 4 waves = 4 buckets. LDS slow path (uniform) for cnt > 64.
// ---------------------------------------------------------------------------
__global__ void __launch_bounds__(256) nms_kernel(
    const int*   __restrict__ cnt_ws,
    const float* __restrict__ rec_ws,
    float* __restrict__ keep_out)
{
  const int tid = threadIdx.x;
  const int wv = tid >> 6;
  const int lane = tid & 63;
  const int bucket0 = blockIdx.x * 4;

  // ---------------- fast path: cnt <= 64, one wave, zero barriers ----------
  {
    const int bucket = bucket0 + wv;
    const int cnt = min(cnt_ws[bucket], CAP2);
    if (cnt > 0 && cnt <= 64) {
      float x1 = 0.f, y1 = 0.f, x2 = 0.f, y2 = 0.f;
      int n = 0;
      unsigned long long key;
      if (lane < cnt) {
        const float* r = rec_ws + ((size_t)bucket * CAP2 + lane) * 6;
        x1 = r[0]; y1 = r[1]; x2 = r[2]; y2 = r[3];
        float sc = r[4];
        n = __float_as_int(r[5]);
        // score >= 0.5 > 0 -> float bit order == value order.
        // key: score desc, then n asc (stable argsort(-score) semantics).
        key = ((unsigned long long)__float_as_uint(sc) << 32) |
              (unsigned)(0x7FFFFFFF - n);
      } else {
        key = (unsigned long long)lane;   // unique tiny pad keys, sink to end
      }
      int src = lane;

      // bitonic sort, descending by key, payload = source lane
      for (int k = 2; k <= 64; k <<= 1) {
        for (int j = k >> 1; j > 0; j >>= 1) {
          unsigned long long ok = __shfl_xor(key, j);
          int osrc = __shfl_xor(src, j);
          bool lower = ((lane & j) == 0);
          bool asc = ((lane & k) != 0);     // inverted -> overall descending
          bool mine_gt = key > ok;          // keys unique (distinct n)
          bool take = asc ? (lower ? mine_gt : !mine_gt)
                          : (lower ? !mine_gt : mine_gt);
          if (take) { key = ok; src = osrc; }
        }
      }

      // gather sorted payload from pre-sort lanes
      float sx1 = __shfl(x1, src), sy1 = __shfl(y1, src);
      float sx2 = __shfl(x2, src), sy2 = __shfl(y2, src);
      int   sn  = __shfl(n, src);
      float area = __fmul_rn(__fadd_rn(__fsub_rn(sx2, sx1), 1.0f),
                             __fadd_rn(__fsub_rn(sy2, sy1), 1.0f));

      // greedy suppression: sup mask replicated in every lane via ballot
      unsigned long long sup = 0ull;
      for (int i = 0; i < cnt; ++i) {
        if ((sup >> i) & 1ull) continue;          // uniform (ballot-broadcast)
        float bx1 = __shfl(sx1, i), by1 = __shfl(sy1, i);
        float bx2 = __shfl(sx2, i), by2 = __shfl(sy2, i);
        float bar = __shfl(area, i);
        bool kill = false;
        if (lane > i && lane < cnt) {
          float iw_ = fmaxf(__fadd_rn(__fsub_rn(fminf(bx2, sx2),
                                                fmaxf(bx1, sx1)), 1.0f), 0.0f);
          float ih_ = fmaxf(__fadd_rn(__fsub_rn(fminf(by2, sy2),
                                                fmaxf(by1, sy1)), 1.0f), 0.0f);
          float inter = __fmul_rn(iw_, ih_);
          float denom = __fadd_rn(__fsub_rn(__fadd_rn(bar, area), inter), 1e-16f);
          kill = __fdiv_rn(inter, denom) >= NMS_TH;
        }
        sup |= __ballot(kill);
      }
      if (lane < cnt && !((sup >> lane) & 1ull)) {
        int b = bucket / NCLS;
        keep_out[b * NN + sn] = 1.0f;
      }
    }
  }

  // ---------------- slow path: cnt > 64 (block-wide, uniform branches) -----
  __syncthreads();

  __shared__ float s_sc[CAP2];
  __shared__ float s_x1[CAP2], s_y1[CAP2], s_x2[CAP2], s_y2[CAP2];
  __shared__ int   s_idx[CAP2];
  __shared__ unsigned char s_sup[CAP2];

  for (int w2 = 0; w2 < 4; ++w2) {
    const int bucket = bucket0 + w2;
    const int cnt = min(cnt_ws[bucket], CAP2);   // same value in all threads
    if (cnt <= 64) continue;                      // uniform branch

    for (int i = tid; i < cnt; i += 256) {
      const float* r = rec_ws + ((size_t)bucket * CAP2 + i) * 6;
      s_x1[i] = r[0]; s_y1[i] = r[1]; s_x2[i] = r[2]; s_y2[i] = r[3];
      s_sc[i] = r[4]; s_idx[i] = __float_as_int(r[5]);
      s_sup[i] = 0;
    }
    __syncthreads();

    int M = 1;
    while (M < cnt) M <<= 1;
    for (int i = cnt + tid; i < M; i += 256) {
      s_sc[i] = -INFINITY; s_idx[i] = INT_MAX;
      s_x1[i] = 0.f; s_y1[i] = 0.f; s_x2[i] = 0.f; s_y2[i] = 0.f;
    }
    __syncthreads();

    for (int k = 2; k <= M; k <<= 1) {
      for (int j = k >> 1; j > 0; j >>= 1) {
        for (int i = tid; i < M; i += 256) {
          int ixj = i ^ j;
          if (ixj > i) {
            float si = s_sc[i], sj = s_sc[ixj];
            int ii = s_idx[i], ij = s_idx[ixj];
            bool before_ij = (si > sj) || (si == sj && ii < ij);
            bool before_ji = (sj > si) || (sj == si && ij < ii);
            bool up = ((i & k) == 0);
            bool dosw = up ? before_ji : before_ij;
            if (dosw) {
              s_sc[i] = sj;  s_sc[ixj] = si;
              s_idx[i] = ij; s_idx[ixj] = ii;
              float t;
              t = s_x1[i]; s_x1[i] = s_x1[ixj]; s_x1[ixj] = t;
              t = s_y1[i]; s_y1[i] = s_y1[ixj]; s_y1[ixj] = t;
              t = s_x2[i]; s_x2[i] = s_x2[ixj]; s_x2[ixj] = t;
              t = s_y2[i]; s_y2[i] = s_y2[ixj]; s_y2[ixj] = t;
            }
          }
        }
        __syncthreads();
      }
    }

    const int b = bucket / NCLS;
    for (int i = 0; i < cnt; ++i) {
      if (!s_sup[i]) {
        float x1i = s_x1[i], y1i = s_y1[i], x2i = s_x2[i], y2i = s_y2[i];
        float ai = __fmul_rn(__fadd_rn(__fsub_rn(x2i, x1i), 1.0f),
                             __fadd_rn(__fsub_rn(y2i, y1i), 1.0f));
        if (tid == 0) keep_out[b * NN + s_idx[i]] = 1.0f;
        for (int j = i + 1 + tid; j < cnt; j += 256) {
          float iw_ = fmaxf(__fadd_rn(__fsub_rn(fminf(x2i, s_x2[j]),
                                                fmaxf(x1i, s_x1[j])), 1.0f), 0.0f);
          float ih_ = fmaxf(__fadd_rn(__fsub_rn(fminf(y2i, s_y2[j]),
                                                fmaxf(y1i, s_y1[j])), 1.0f), 0.0f);
          float inter = __fmul_rn(iw_, ih_);
          float aj = __fmul_rn(__fadd_rn(__fsub_rn(s_x2[j], s_x1[j]), 1.0f),
                               __fadd_rn(__fsub_rn(s_y2[j], s_y1[j]), 1.0f));
          float denom = __fadd_rn(__fsub_rn(__fadd_rn(ai, aj), inter), 1e-16f);
          if (__fdiv_rn(inter, denom) >= NMS_TH) s_sup[j] = 1;
        }
      }
      __syncthreads();
    }
    __syncthreads();
  }
}

// ---------------------------------------------------------------------------
extern "C" void kernel_launch(void* const* d_in, const int* in_sizes, int n_in,
                              void* d_out, int out_size, void* d_ws, size_t ws_size,
                              hipStream_t stream) {
  const float* pred = (const float*)d_in[0];
  const int* fhp = (const int*)d_in[1];
  const int* fwp = (const int*)d_in[2];

  float* det_out  = (float*)d_out;                  // BB*NN*7
  float* keep_out = det_out + (size_t)BB * NN * 7;  // BB*NN

  int*   cnt_ws = (int*)d_ws;                       // bytes [0, 1280)
  float* rec_ws = (float*)((char*)d_ws + 4096);     // disjoint from cnt_ws

  zero_kernel<<<1, NB, 0, stream>>>(cnt_ws);

  int nThreads = BB * NN;
  prep_kernel<<<(nThreads + 255) / 256, 256, 0, stream>>>(
      pred, fhp, fwp, det_out, keep_out, cnt_ws, rec_ws);

  nms_kernel<<<NB / 4, 256, 0, stream>>>(cnt_ws, rec_ws, keep_out);
}